// Round 11
// baseline (741.523 us; speedup 1.0000x reference)
//
#include <hip/hip_runtime.h>
#include <hip/hip_bf16.h>
#include <math.h>

#define BB 128
#define TT 128
#define VV 64
#define DD 32
#define NQ 5

typedef short bf16x8 __attribute__((ext_vector_type(8)));
typedef float f32x4 __attribute__((ext_vector_type(4)));

#define MFMA(a,b,c) __builtin_amdgcn_mfma_f32_16x16x32_bf16(a,b,c,0,0,0)

__device__ __forceinline__ float sigm(float x){ return 1.0f/(1.0f+__expf(-x)); }
__device__ __forceinline__ float tanhfast(float x){ return 2.0f/(1.0f+__expf(-2.0f*x)) - 1.0f; }
__device__ __forceinline__ unsigned short f2bf(float x){
  unsigned u = __float_as_uint(x);
  u += 0x7FFFu + ((u>>16)&1u);
  return (unsigned short)(u>>16);
}
__device__ __forceinline__ float bf2f(unsigned short h){
  return __uint_as_float(((unsigned)h)<<16);
}

union bfu { bf16x8 v; unsigned u[4]; unsigned short s[8]; };

// split 8 floats -> hi bf16x8 + lo bf16x8 (lo = rne(x - f32(hi))) via cvt_pk (RNE)
__device__ __forceinline__ void split8(const float* x, bfu& H, bfu& L){
  #pragma unroll
  for (int i = 0; i < 4; ++i){
    const float a = x[2*i], c = x[2*i+1];
    const __hip_bfloat162 hp = __float22bfloat162_rn(make_float2(a, c));
    unsigned hu; __builtin_memcpy(&hu, &hp, 4);
    H.u[i] = hu;
    const float ah = __uint_as_float(hu << 16);
    const float ch = __uint_as_float(hu & 0xFFFF0000u);
    const __hip_bfloat162 lp = __float22bfloat162_rn(make_float2(a - ah, c - ch));
    unsigned lu; __builtin_memcpy(&lu, &lp, 4);
    L.u[i] = lu;
  }
}

// ---------------- precompute kernels ----------------

__global__ __launch_bounds__(64)
void k_mlp(const float* __restrict__ Pplm,
           const float* __restrict__ Ws1, const float* __restrict__ bs1,
           const float* __restrict__ Ws2, const float* __restrict__ bs2,
           const float* __restrict__ Wg1, const float* __restrict__ bg1,
           const float* __restrict__ Wg2, const float* __restrict__ bg2,
           float* __restrict__ vv_ws, float* __restrict__ gn_ws)
{
  __shared__ float sH[64], sG[64], sgv[8];
  const int v = blockIdx.x, j = threadIdx.x;
  float a = bs1[j], g = bg1[j];
  for (int k = 0; k < 768; ++k){
    const float p = Pplm[v*768 + k];
    a = fmaf(p, Ws1[k*64 + j], a);
    g = fmaf(p, Wg1[k*64 + j], g);
  }
  sH[j] = fmaxf(a, 0.f);
  sG[j] = fmaxf(g, 0.f);
  __syncthreads();
  if (j < 5){
    float acc = bs2[j];
    for (int k = 0; k < 64; ++k) acc = fmaf(sH[k], Ws2[k*5 + j], acc);
    vv_ws[v*5 + j] = acc;
  }
  if (j < 8){
    float acc = bg2[j];
    for (int k = 0; k < 64; ++k) acc = fmaf(sG[k], Wg2[k*8 + j], acc);
    sgv[j] = acc;
  }
  __syncthreads();
  if (j == 0){
    float n = 0.f;
    for (int e = 0; e < 8; ++e) n += sgv[e]*sgv[e];
    n = fmaxf(sqrtf(n), 1e-12f);
    for (int e = 0; e < 8; ++e) gn_ws[v*8 + e] = sgv[e]/n;
  }
}

__global__ __launch_bounds__(64)
void k_adj(const float* __restrict__ gn_ws, float* __restrict__ adj_ws)
{
  const int v = blockIdx.x, j = threadIdx.x;
  float sc = 0.f;
  #pragma unroll
  for (int e = 0; e < 8; ++e) sc += gn_ws[v*8+e]*gn_ws[j*8+e];
  float mx = sc;
  for (int off = 32; off > 0; off >>= 1) mx = fmaxf(mx, __shfl_xor(mx, off));
  const float ex = __expf(sc - mx);
  float sm = ex;
  for (int off = 32; off > 0; off >>= 1) sm += __shfl_xor(sm, off);
  adj_ws[v*64 + j] = ex / sm;
}

__global__ __launch_bounds__(256)
void k_vto(const float* __restrict__ P, float* __restrict__ vto_ws)
{
  const int idx = blockIdx.x*256 + threadIdx.x;
  if (idx >= BB*VV) return;
  const int b = idx/VV, v = idx%VV;
  float s = 0.f;
  for (int t = 0; t < TT; ++t) s += P[((size_t)(b*TT+t))*128 + 64 + v];
  vto_ws[idx] = s;
}

// pack gate weights into per-lane MFMA B-fragments (bf16) + paired side tables
// frag id f = ((e*2 + kt)*2 + p); element (f*64 + lane)*8 + j
// ALL gates use K-order [x(0..31) | h(0..31)] with rarity (orig k=32) as side:
//   k' = kt*32 + (lane>>4)*8 + j ; orig_k = (k'<32) ? k' : k'+1
// side tables: [e][o][2] pairs -> {rarity weight, bias}
__global__ __launch_bounds__(256)
void k_bpack(const float* __restrict__ Wr, const float* __restrict__ br,
             const float* __restrict__ Wu, const float* __restrict__ bu,
             const float* __restrict__ Wc, const float* __restrict__ bc,
             unsigned short* __restrict__ Bru, unsigned short* __restrict__ Bcn,
             float* __restrict__ sideRU, float* __restrict__ sideC)
{
  const int idx = blockIdx.x*256 + threadIdx.x;
  if (idx < 20480){
    const int f = idx >> 9, rem = idx & 511, l = rem >> 3, j = rem & 7;
    const int p = f & 1, kt = (f>>1)&1, e = f>>2;
    const int kp = kt*32 + (l>>4)*8 + j;
    const int k = (kp < 32) ? kp : kp + 1;
    const int o = p*16 + (l&15);
    const int q = (e < 5) ? e : e - 5;
    const float* W = (e < 5) ? Wr : Wu;
    Bru[idx] = f2bf(W[(q*65 + k)*32 + o]);
  } else if (idx < 30720){
    const int i2 = idx - 20480;
    const int f = i2 >> 9, rem = i2 & 511, l = rem >> 3, j = rem & 7;
    const int p = f & 1, kt = (f>>1)&1, e = f>>2;
    const int kp = kt*32 + (l>>4)*8 + j;
    const int k = (kp < 32) ? kp : kp + 1;
    const int o = p*16 + (l&15);
    Bcn[i2] = f2bf(Wc[(e*65 + k)*32 + o]);
  } else if (idx < 31360){
    const int i3 = idx - 30720;            // [e:10][o:32][s:2] pairs
    const int e = i3 >> 6, rem = i3 & 63, o = rem >> 1, s = rem & 1;
    const int q = (e < 5) ? e : e - 5;
    float v;
    if (s == 0) v = (e < 5) ? Wr[(q*65 + 32)*32 + o] : Wu[(q*65 + 32)*32 + o]; // rarity weight
    else        v = (e < 5) ? br[q*32 + o] : bu[q*32 + o];
    sideRU[i3] = v;
  } else if (idx < 31680){
    const int i4 = idx - 31360;            // [e:5][o:32][s:2] pairs
    const int e = i4 >> 6, rem = i4 & 63, o = rem >> 1, s = rem & 1;
    sideC[i4] = s ? bc[e*32 + o] : Wc[(e*65 + 32)*32 + o];   // s=0: rarity weight
  }
}

// ---------------- main recurrent kernel: 1 block (768 thr / 12 waves) per batch ----------------
// waves 0..7 = work (r9 structure): wave (mq=wid>>1, ph=wid&1), rows R..R+15, o-half ph.
// waves 8..11 = prep (one per mq): build step-t+1 rar/m, x->B0T, adj A-fragments -> sFragA,
// comb_rar -> s_crar. All handoffs covered by the 3 existing barriers.

__global__ __launch_bounds__(768, 1)
void tedgn_main(const float* __restrict__ P, const float* __restrict__ Pstatic,
                const float* __restrict__ Pavg, const int* __restrict__ Plen,
                const float* __restrict__ Ptime,
                const float* __restrict__ w_val, const float* __restrict__ b_val,
                const float* __restrict__ w_per, const float* __restrict__ b_per,
                const float* __restrict__ w_lin, const float* __restrict__ b_lin,
                const float* __restrict__ emb1, const float* __restrict__ rarW,
                const float* __restrict__ Wse, const float* __restrict__ bse,
                const float* __restrict__ Wc1, const float* __restrict__ bc1,
                const float* __restrict__ Wc2, const float* __restrict__ bc2,
                const float* __restrict__ vv_ws, const float* __restrict__ adjb_ws,
                const float* __restrict__ vto_ws,
                const unsigned short* __restrict__ Bru_ws,
                const unsigned short* __restrict__ Bc_ws,
                const float* __restrict__ sideRU_ws, const float* __restrict__ sideC_ws,
                float* __restrict__ out)
{
  // XH^T double-buffered: [buf][hi/lo][feature 0..63 = x(32)|h(32)][v, pad 72]
  __shared__ __align__(16) unsigned short B0T[2][2][64][72];
  __shared__ __align__(16) unsigned short s_Wru[20480];
  __shared__ __align__(16) unsigned short s_Wc[10240];
  __shared__ __align__(16) unsigned short sFragA[2][4][2][2][64][8]; // [buf][mq][kt][hi/lo][lane][8]
  __shared__ __align__(16) float A1f[4][16][68];   // per-mq comb rows (f32)
  __shared__ __align__(16) float hrF[4][16][36];   // per-mq h_r rows (f32)
  __shared__ __align__(16) float s_rar[2][64];
  __shared__ __align__(16) float s_m[2][64];
  __shared__ float s_crar[2][64];
  __shared__ float s_sru[640], s_scd[320];

  const int tid  = threadIdx.x;
  const int lane = tid & 63;
  const int wid  = tid >> 6;      // 12 waves
  const bool isWork = (wid < 8);
  const int mq   = isWork ? (wid >> 1) : (wid - 8);
  const int ph   = wid & 1;       // work waves only
  const int l15  = lane & 15;
  const int l16g = lane >> 4;
  const int kgo  = l16g * 8;
  const int R    = mq * 16;
  const int v_own = R + l15;
  const int oo   = ph*16 + l15;
  const int b    = blockIdx.x;
  const int len  = Plen[b];

  // LDS fills
  for (int i = tid; i < 640; i += 768) s_sru[i] = sideRU_ws[i];
  for (int i = tid; i < 320; i += 768) s_scd[i] = sideC_ws[i];
  {
    const uint4* src1 = (const uint4*)Bru_ws;
    uint4* dst1 = (uint4*)s_Wru;
    for (int i = tid; i < 2560; i += 768) dst1[i] = src1[i];
    const uint4* src2 = (const uint4*)Bc_ws;
    uint4* dst2 = (uint4*)s_Wc;
    for (int i = tid; i < 1280; i += 768) dst2[i] = src2[i];
  }

  // constants common to both roles (x-build coefficients)
  float embr[8], wvr[8], bvr[8], wpr[8], bpr[8];
  #pragma unroll
  for (int j = 0; j < 8; ++j){
    const int d = kgo + j;
    embr[j] = emb1[v_own*DD + d];
    wvr[j]  = w_val[d];
    bvr[j]  = b_val[d];
    wpr[j]  = (d == 0) ? w_lin[0] : w_per[d-1];
    bpr[j]  = (d == 0) ? b_lin[0] : b_per[d-1];
  }

  // role-specific constants
  float adjb_r[2][8], rarW_r[2][8];     // prep only
  float vto_own = 0.f;                  // prep only
  float vvr[4][NQ];                     // work only
  if (!isWork){
    #pragma unroll
    for (int kt = 0; kt < 2; ++kt)
      #pragma unroll
      for (int j = 0; j < 8; ++j){
        adjb_r[kt][j] = adjb_ws[v_own*64 + kt*32 + kgo + j];
        rarW_r[kt][j] = rarW   [v_own*64 + kt*32 + kgo + j];
      }
    vto_own = vto_ws[b*VV + v_own];
  } else {
    #pragma unroll
    for (int j = 0; j < 4; ++j)
      #pragma unroll
      for (int q = 0; q < NQ; ++q)
        vvr[j][q] = vv_ws[(R + l16g*4 + j)*NQ + q];
  }

  float h[4]    = {0.f,0.f,0.f,0.f};
  float outr[4] = {0.f,0.f,0.f,0.f};
  bfu xfH, xfL, xfnH, xfnL;
  float pp_pd = 0.f, pp_pm = 0.f, pp_pt = 0.f, pp_rar = 0.f;  // prep part(a) regs

  // ---- prologue ----
  if (isWork){
    // build xv(0) -> xf regs; zero B0T[0] h rows
    const float pd = P[(size_t)(b*TT)*128 + v_own];
    const float pm = P[(size_t)(b*TT)*128 + 64 + v_own];
    const float pt = Ptime[b*TT];
    float xv[8];
    #pragma unroll
    for (int j = 0; j < 8; ++j){
      const int d = kgo + j;
      const float tearg = fmaf(pt, wpr[j], bpr[j]);
      const float te = (d == 0) ? tearg : __sinf(tearg);
      const float ve = fmaxf(fmaf(pd, wvr[j], bvr[j]), 0.f);
      xv[j] = (ve + te + embr[j]) * pm;
    }
    split8(xv, xfH, xfL);
    if (ph == 0){
      *(uint2*)&B0T[0][0][32 + l15][R + l16g*4] = make_uint2(0u, 0u);
      *(uint2*)&B0T[0][1][32 + l15][R + l16g*4] = make_uint2(0u, 0u);
    } else {
      *(uint2*)&B0T[0][0][48 + l15][R + l16g*4] = make_uint2(0u, 0u);
      *(uint2*)&B0T[0][1][48 + l15][R + l16g*4] = make_uint2(0u, 0u);
    }
  } else {
    // prep part(a) for t=0
    pp_pd = P[(size_t)(b*TT)*128 + v_own];
    pp_pm = P[(size_t)(b*TT)*128 + 64 + v_own];
    const float pa = Pavg[(size_t)(b*TT)*VV + v_own];
    pp_pt = Ptime[b*TT];
    pp_rar = 0.5f * tanhfast(pa / (vto_own + 1.f));
    if (l16g == 0){
      s_rar[0][v_own] = pp_rar;
      s_m[0][v_own]   = pp_pm;
    }
  }
  __syncthreads();
  if (!isWork){
    // prep part(b) for t=0: x -> B0T[0], adj frags -> sFragA[0], crar -> s_crar[0]
    float xv[8];
    #pragma unroll
    for (int j = 0; j < 8; ++j){
      const int d = kgo + j;
      const float tearg = fmaf(pp_pt, wpr[j], bpr[j]);
      const float te = (d == 0) ? tearg : __sinf(tearg);
      const float ve = fmaxf(fmaf(pp_pd, wvr[j], bvr[j]), 0.f);
      xv[j] = (ve + te + embr[j]) * pp_pm;
    }
    bfu xh, xl;
    split8(xv, xh, xl);
    #pragma unroll
    for (int j = 0; j < 8; ++j){
      B0T[0][0][kgo + j][v_own] = xh.s[j];
      B0T[0][1][kgo + j][v_own] = xl.s[j];
    }
    bfu aAh[2], aAl[2];
    float crar = 0.f;
    #pragma unroll
    for (int kt = 0; kt < 2; ++kt){
      const float4 r0 = *(const float4*)&s_rar[0][kt*32 + kgo];
      const float4 r1 = *(const float4*)&s_rar[0][kt*32 + kgo + 4];
      const float4 m0 = *(const float4*)&s_m[0][kt*32 + kgo];
      const float4 m1 = *(const float4*)&s_m[0][kt*32 + kgo + 4];
      const float rj[8] = {r0.x,r0.y,r0.z,r0.w,r1.x,r1.y,r1.z,r1.w};
      const float mj[8] = {m0.x,m0.y,m0.z,m0.w,m1.x,m1.y,m1.z,m1.w};
      float av[8];
      #pragma unroll
      for (int j = 0; j < 8; ++j){
        const int k = kt*32 + kgo + j;
        const float e1 = fmaf(-rarW_r[kt][j], fabsf(pp_rar - rj[j]), 1.0f);
        const float a  = adjb_r[kt][j] * e1 * (pp_pm * mj[j]);
        av[j] = (k == v_own) ? 1.0f : a;
        crar = fmaf(av[j], rj[j], crar);
      }
      split8(av, aAh[kt], aAl[kt]);
    }
    crar += __shfl_xor(crar, 16);
    crar += __shfl_xor(crar, 32);
    if (l16g == 0) s_crar[0][v_own] = crar;
    #pragma unroll
    for (int kt = 0; kt < 2; ++kt){
      *(bf16x8*)&sFragA[0][mq][kt][0][lane][0] = aAh[kt].v;
      *(bf16x8*)&sFragA[0][mq][kt][1][lane][0] = aAl[kt].v;
    }
  }
  __syncthreads();

  #pragma clang loop unroll(disable)
  for (int t = 0; t < TT; ++t){
    const int cur = t & 1, nxt = cur ^ 1;
    const bool more = (t + 1 < TT);

    if (isWork){
      // ---- Phase A: load adj frags, comb MFMA, store A1f; build xfn(t+1) ----
      float pd = 0.f, pm = 0.f, pt = 0.f;
      if (more){
        pd = P[(size_t)(b*TT + t + 1)*128 + v_own];
        pm = P[(size_t)(b*TT + t + 1)*128 + 64 + v_own];
        pt = Ptime[b*TT + t + 1];
      }
      bf16x8 aAh0 = *(const bf16x8*)&sFragA[cur][mq][0][0][lane][0];
      bf16x8 aAl0 = *(const bf16x8*)&sFragA[cur][mq][0][1][lane][0];
      bf16x8 aAh1 = *(const bf16x8*)&sFragA[cur][mq][1][0][lane][0];
      bf16x8 aAl1 = *(const bf16x8*)&sFragA[cur][mq][1][1][lane][0];
      #pragma unroll
      for (int ni = 0; ni < 2; ++ni){
        const int n = 2*ph + ni;
        f32x4 acc = {0.f,0.f,0.f,0.f};
        {
          const bf16x8 bh0 = *(const bf16x8*)&B0T[cur][0][n*16 + l15][kgo];
          const bf16x8 bl0 = *(const bf16x8*)&B0T[cur][1][n*16 + l15][kgo];
          acc = MFMA(aAh0, bh0, acc);
          acc = MFMA(aAl0, bh0, acc);
          acc = MFMA(aAh0, bl0, acc);
          const bf16x8 bh1 = *(const bf16x8*)&B0T[cur][0][n*16 + l15][32 + kgo];
          const bf16x8 bl1 = *(const bf16x8*)&B0T[cur][1][n*16 + l15][32 + kgo];
          acc = MFMA(aAh1, bh1, acc);
          acc = MFMA(aAl1, bh1, acc);
          acc = MFMA(aAh1, bl1, acc);
        }
        const int col = n*16 + l15;
        #pragma unroll
        for (int j = 0; j < 4; ++j) A1f[mq][l16g*4 + j][col] = acc[j];
      }
      // xfn build (independent; fills MFMA shadow)
      if (more){
        float xv[8];
        #pragma unroll
        for (int j = 0; j < 8; ++j){
          const int d = kgo + j;
          const float tearg = fmaf(pt, wpr[j], bpr[j]);
          const float te = (d == 0) ? tearg : __sinf(tearg);
          const float ve = fmaxf(fmaf(pd, wvr[j], bvr[j]), 0.f);
          xv[j] = (ve + te + embr[j]) * pm;
        }
        split8(xv, xfnH, xfnL);
      }
    } else if (more){
      // ---- prep part(a): rar/m for t+1 ----
      pp_pd = P[(size_t)(b*TT + t + 1)*128 + v_own];
      pp_pm = P[(size_t)(b*TT + t + 1)*128 + 64 + v_own];
      const float pa = Pavg[(size_t)(b*TT + t + 1)*VV + v_own];
      pp_pt = Ptime[b*TT + t + 1];
      pp_rar = 0.5f * tanhfast(pa / (vto_own + 1.f));
      if (l16g == 0){
        s_rar[nxt][v_own] = pp_rar;
        s_m[nxt][v_own]   = pp_pm;
      }
    }
    __syncthreads();   // barrier 1: A1f + s_rar[nxt] complete

    float hr[4], uu[4];
    if (isWork){
      // ---- Phase B: gate A-fragments + r/u gates ----
      bfu aH[2], aL[2];
      #pragma unroll
      for (int kt = 0; kt < 2; ++kt){
        float xv[8];
        *(float4*)&xv[0] = *(const float4*)&A1f[mq][l15][kt*32 + kgo];
        *(float4*)&xv[4] = *(const float4*)&A1f[mq][l15][kt*32 + kgo + 4];
        split8(xv, aH[kt], aL[kt]);
      }
      float a64f[4];
      #pragma unroll
      for (int j = 0; j < 4; ++j) a64f[j] = s_crar[cur][R + l16g*4 + j];

      f32x4 ag[10];
      #pragma unroll
      for (int e = 0; e < 10; ++e){
        const float2 wb = *(const float2*)&s_sru[e*64 + oo*2];
        #pragma unroll
        for (int j = 0; j < 4; ++j) ag[e][j] = fmaf(a64f[j], wb.x, wb.y);
      }
      #pragma unroll
      for (int e = 0; e < 10; ++e){
        const bf16x8 w0 = *(const bf16x8*)&s_Wru[(((e*2+0)*2+ph)*64 + lane)*8];
        const bf16x8 w1 = *(const bf16x8*)&s_Wru[(((e*2+1)*2+ph)*64 + lane)*8];
        ag[e] = MFMA(aH[0].v, w0, ag[e]);
        ag[e] = MFMA(aL[0].v, w0, ag[e]);
        ag[e] = MFMA(aH[1].v, w1, ag[e]);
        ag[e] = MFMA(aL[1].v, w1, ag[e]);
      }
      #pragma unroll
      for (int j = 0; j < 4; ++j){
        const float pr = vvr[j][0]*ag[0][j] + vvr[j][1]*ag[1][j]
                       + vvr[j][2]*ag[2][j] + vvr[j][3]*ag[3][j]
                       + vvr[j][4]*ag[4][j];
        hr[j] = sigm(pr) * h[j];
        hrF[mq][l16g*4 + j][oo] = hr[j];
      }
      #pragma unroll
      for (int j = 0; j < 4; ++j){
        const float pu = vvr[j][0]*ag[5][j] + vvr[j][1]*ag[6][j]
                       + vvr[j][2]*ag[7][j] + vvr[j][3]*ag[8][j]
                       + vvr[j][4]*ag[9][j];
        uu[j] = sigm(pu);
      }
    } else if (more){
      // ---- prep part(b): x(t+1) -> B0T[nxt]; adj(t+1) -> sFragA[nxt]; crar ----
      float xv[8];
      #pragma unroll
      for (int j = 0; j < 8; ++j){
        const int d = kgo + j;
        const float tearg = fmaf(pp_pt, wpr[j], bpr[j]);
        const float te = (d == 0) ? tearg : __sinf(tearg);
        const float ve = fmaxf(fmaf(pp_pd, wvr[j], bvr[j]), 0.f);
        xv[j] = (ve + te + embr[j]) * pp_pm;
      }
      bfu xh, xl;
      split8(xv, xh, xl);
      #pragma unroll
      for (int j = 0; j < 8; ++j){
        B0T[nxt][0][kgo + j][v_own] = xh.s[j];
        B0T[nxt][1][kgo + j][v_own] = xl.s[j];
      }
      bfu aAh[2], aAl[2];
      float crar = 0.f;
      #pragma unroll
      for (int kt = 0; kt < 2; ++kt){
        const float4 r0 = *(const float4*)&s_rar[nxt][kt*32 + kgo];
        const float4 r1 = *(const float4*)&s_rar[nxt][kt*32 + kgo + 4];
        const float4 m0 = *(const float4*)&s_m[nxt][kt*32 + kgo];
        const float4 m1 = *(const float4*)&s_m[nxt][kt*32 + kgo + 4];
        const float rj[8] = {r0.x,r0.y,r0.z,r0.w,r1.x,r1.y,r1.z,r1.w};
        const float mj[8] = {m0.x,m0.y,m0.z,m0.w,m1.x,m1.y,m1.z,m1.w};
        float av[8];
        #pragma unroll
        for (int j = 0; j < 8; ++j){
          const int k = kt*32 + kgo + j;
          const float e1 = fmaf(-rarW_r[kt][j], fabsf(pp_rar - rj[j]), 1.0f);
          const float a  = adjb_r[kt][j] * e1 * (pp_pm * mj[j]);
          av[j] = (k == v_own) ? 1.0f : a;
          crar = fmaf(av[j], rj[j], crar);
        }
        split8(av, aAh[kt], aAl[kt]);
      }
      crar += __shfl_xor(crar, 16);
      crar += __shfl_xor(crar, 32);
      if (l16g == 0) s_crar[nxt][v_own] = crar;
      #pragma unroll
      for (int kt = 0; kt < 2; ++kt){
        *(bf16x8*)&sFragA[nxt][mq][kt][0][lane][0] = aAh[kt].v;
        *(bf16x8*)&sFragA[nxt][mq][kt][1][lane][0] = aAl[kt].v;
      }
    }
    __syncthreads();   // barrier 2: hrF complete

    if (isWork){
      // ---- Phase C: cand + GRU update + B0T[nxt] h-write ----
      bfu hH, hL;
      {
        float hv[8];
        *(float4*)&hv[0] = *(const float4*)&hrF[mq][l15][kgo];
        *(float4*)&hv[4] = *(const float4*)&hrF[mq][l15][kgo + 4];
        split8(hv, hH, hL);
      }
      float rar_cj[4], m_cj[4];
      #pragma unroll
      for (int j = 0; j < 4; ++j){
        rar_cj[j] = s_rar[cur][R + l16g*4 + j];
        m_cj[j]   = s_m[cur][R + l16g*4 + j];
      }
      f32x4 ag[5];
      #pragma unroll
      for (int e = 0; e < 5; ++e){
        const float2 wb = *(const float2*)&s_scd[e*64 + oo*2];
        #pragma unroll
        for (int j = 0; j < 4; ++j) ag[e][j] = fmaf(rar_cj[j], wb.x, wb.y);
      }
      #pragma unroll
      for (int e = 0; e < 5; ++e){
        const bf16x8 w0 = *(const bf16x8*)&s_Wc[(((e*2+0)*2+ph)*64 + lane)*8];
        const bf16x8 w1 = *(const bf16x8*)&s_Wc[(((e*2+1)*2+ph)*64 + lane)*8];
        ag[e] = MFMA(xfH.v, w0, ag[e]);
        ag[e] = MFMA(xfL.v, w0, ag[e]);
        ag[e] = MFMA(hH.v,  w1, ag[e]);
        ag[e] = MFMA(hL.v,  w1, ag[e]);
      }
      const bool snap = (t == len - 1);
      #pragma unroll
      for (int j = 0; j < 4; ++j){
        const float pc = vvr[j][0]*ag[0][j] + vvr[j][1]*ag[1][j]
                       + vvr[j][2]*ag[2][j] + vvr[j][3]*ag[3][j]
                       + vvr[j][4]*ag[4][j];
        const float cd = tanhfast(pc);
        const float hn = fmaf(uu[j], cd - hr[j], hr[j]);
        const float hf = (m_cj[j] > 0.5f) ? hn : h[j];
        h[j] = hf;
        if (snap) outr[j] = hf;
      }
      // write h to B0T[nxt] row 32+oo, cols R+l16g*4..+3
      {
        unsigned H2[2], L2[2];
        #pragma unroll
        for (int i = 0; i < 2; ++i){
          const float a = h[2*i], c = h[2*i+1];
          const __hip_bfloat162 hp = __float22bfloat162_rn(make_float2(a, c));
          unsigned hu; __builtin_memcpy(&hu, &hp, 4);
          H2[i] = hu;
          const float ah = __uint_as_float(hu << 16);
          const float ch = __uint_as_float(hu & 0xFFFF0000u);
          const __hip_bfloat162 lp = __float22bfloat162_rn(make_float2(a - ah, c - ch));
          unsigned lu; __builtin_memcpy(&lu, &lp, 4);
          L2[i] = lu;
        }
        *(uint2*)&B0T[nxt][0][32 + oo][R + l16g*4] = make_uint2(H2[0], H2[1]);
        *(uint2*)&B0T[nxt][1][32 + oo][R + l16g*4] = make_uint2(L2[0], L2[1]);
      }
      if (more){ xfH = xfnH; xfL = xfnL; }
    }
    __syncthreads();   // barrier 3: step complete
  }

  // ---- epilogue: feat -> 200-unit MLP -> 2 logits (aliased into sFragA pool) ----
  float* s_outf = (float*)sFragA;           // [64][33]
  float* s_feat = s_outf + 64*33;           // [128]
  float* s_hid  = s_feat + 128;             // [200]
  if (isWork){
    #pragma unroll
    for (int j = 0; j < 4; ++j)
      s_outf[(R + l16g*4 + j)*33 + oo] = outr[j];
  }
  __syncthreads();
  if (tid < VV){
    float s = 0.f;
    #pragma unroll
    for (int d = 0; d < DD; ++d) s += s_outf[tid*33 + d];
    s_feat[tid] = s;
  } else if (tid < 2*VV){
    const int v = tid - VV;
    float se = bse[v];
    #pragma unroll
    for (int k = 0; k < 16; ++k) se = fmaf(Pstatic[b*16 + k], Wse[k*VV + v], se);
    s_feat[VV + v] = se;
  }
  __syncthreads();
  if (tid < 200){
    float a = bc1[tid];
    for (int k = 0; k < 128; ++k) a = fmaf(s_feat[k], Wc1[k*200 + tid], a);
    s_hid[tid] = fmaxf(a, 0.f);
  }
  __syncthreads();
  if (tid < 2){
    float a = bc2[tid];
    for (int k = 0; k < 200; ++k) a = fmaf(s_hid[k], Wc2[k*2 + tid], a);
    out[b*2 + tid] = a;
  }
}

// ---------------- launch ----------------

extern "C" void kernel_launch(void* const* d_in, const int* in_sizes, int n_in,
                              void* d_out, int out_size, void* d_ws, size_t ws_size,
                              hipStream_t stream) {
  (void)in_sizes; (void)n_in; (void)out_size; (void)ws_size;
  const float* P       = (const float*)d_in[0];
  const float* Pstatic = (const float*)d_in[1];
  const float* Pavg    = (const float*)d_in[2];
  const int*   Plen    = (const int*)  d_in[3];
  const float* Ptime   = (const float*)d_in[4];
  const float* Pplm    = (const float*)d_in[5];
  const float* w_val   = (const float*)d_in[6];
  const float* b_val   = (const float*)d_in[7];
  const float* w_per   = (const float*)d_in[8];
  const float* b_per   = (const float*)d_in[9];
  const float* w_lin   = (const float*)d_in[10];
  const float* b_lin   = (const float*)d_in[11];
  const float* emb1    = (const float*)d_in[12];
  const float* Ws1     = (const float*)d_in[13];
  const float* bs1     = (const float*)d_in[14];
  const float* Ws2     = (const float*)d_in[15];
  const float* bs2     = (const float*)d_in[16];
  const float* Wg1     = (const float*)d_in[17];
  const float* bg1     = (const float*)d_in[18];
  const float* Wg2     = (const float*)d_in[19];
  const float* bg2     = (const float*)d_in[20];
  const float* rarW    = (const float*)d_in[21];
  const float* Wu      = (const float*)d_in[22];
  const float* bu      = (const float*)d_in[23];
  const float* Wr      = (const float*)d_in[24];
  const float* br      = (const float*)d_in[25];
  const float* Wcand   = (const float*)d_in[26];
  const float* bcand   = (const float*)d_in[27];
  const float* Wse     = (const float*)d_in[28];
  const float* bse     = (const float*)d_in[29];
  const float* Wc1     = (const float*)d_in[30];
  const float* bc1     = (const float*)d_in[31];
  const float* Wc2     = (const float*)d_in[32];
  const float* bc2     = (const float*)d_in[33];

  float* ws = (float*)d_ws;
  float*          vv_ws   = ws;                 // 320 f
  float*          gn_ws   = ws + 320;           // 512 f
  float*          adjb_ws = ws + 832;           // 4096 f
  float*          vto_ws  = ws + 4928;          // 8192 f
  unsigned short* Bru_ws  = (unsigned short*)(ws + 13120);   // 20480 u16
  unsigned short* Bc_ws   = (unsigned short*)(ws + 23360);   // 10240 u16
  float*          sideRU_ws = ws + 28480;       // 640 f
  float*          sideC_ws  = ws + 29120;       // 320 f

  k_mlp  <<<64, 64, 0, stream>>>(Pplm, Ws1, bs1, Ws2, bs2, Wg1, bg1, Wg2, bg2, vv_ws, gn_ws);
  k_adj  <<<64, 64, 0, stream>>>(gn_ws, adjb_ws);
  k_vto  <<<(BB*VV + 255)/256, 256, 0, stream>>>(P, vto_ws);
  k_bpack<<<124, 256, 0, stream>>>(Wr, br, Wu, bu, Wcand, bcand, Bru_ws, Bc_ws, sideRU_ws, sideC_ws);

  tedgn_main<<<BB, 768, 0, stream>>>(P, Pstatic, Pavg, Plen, Ptime,
                                     w_val, b_val, w_per, b_per, w_lin, b_lin,
                                     emb1, rarW, Wse, bse, Wc1, bc1, Wc2, bc2,
                                     vv_ws, adjb_ws, vto_ws,
                                     Bru_ws, Bc_ws, sideRU_ws, sideC_ws,
                                     (float*)d_out);
}

// Round 12
// 583.757 us; speedup vs baseline: 1.2703x; 1.2703x over previous
//
#include <hip/hip_runtime.h>
#include <hip/hip_bf16.h>
#include <math.h>

#define BB 128
#define TT 128
#define VV 64
#define DD 32
#define NQ 5

typedef short bf16x8 __attribute__((ext_vector_type(8)));
typedef float f32x4 __attribute__((ext_vector_type(4)));

#define MFMA(a,b,c) __builtin_amdgcn_mfma_f32_16x16x32_bf16(a,b,c,0,0,0)

// barrier with LDS-only drain: DS producer/consumer ordering preserved via
// lgkmcnt(0); global loads (register-private prefetch) stay in flight.
__device__ __forceinline__ void bar_lgkm(){
  asm volatile("s_waitcnt lgkmcnt(0)" ::: "memory");
  __builtin_amdgcn_s_barrier();
  asm volatile("" ::: "memory");
}

__device__ __forceinline__ float sigm(float x){ return 1.0f/(1.0f+__expf(-x)); }
__device__ __forceinline__ float tanhfast(float x){ return 2.0f/(1.0f+__expf(-2.0f*x)) - 1.0f; }
__device__ __forceinline__ unsigned short f2bf(float x){
  unsigned u = __float_as_uint(x);
  u += 0x7FFFu + ((u>>16)&1u);
  return (unsigned short)(u>>16);
}
__device__ __forceinline__ float bf2f(unsigned short h){
  return __uint_as_float(((unsigned)h)<<16);
}

union bfu { bf16x8 v; unsigned u[4]; unsigned short s[8]; };

// split 8 floats -> hi bf16x8 + lo bf16x8 (lo = rne(x - f32(hi))) via cvt_pk (RNE)
__device__ __forceinline__ void split8(const float* x, bfu& H, bfu& L){
  #pragma unroll
  for (int i = 0; i < 4; ++i){
    const float a = x[2*i], c = x[2*i+1];
    const __hip_bfloat162 hp = __float22bfloat162_rn(make_float2(a, c));
    unsigned hu; __builtin_memcpy(&hu, &hp, 4);
    H.u[i] = hu;
    const float ah = __uint_as_float(hu << 16);
    const float ch = __uint_as_float(hu & 0xFFFF0000u);
    const __hip_bfloat162 lp = __float22bfloat162_rn(make_float2(a - ah, c - ch));
    unsigned lu; __builtin_memcpy(&lu, &lp, 4);
    L.u[i] = lu;
  }
}

// split 4 floats -> 2x uint (4 bf16 hi) + 2x uint (4 bf16 lo)
__device__ __forceinline__ void split4(const float* x, unsigned* H, unsigned* L){
  #pragma unroll
  for (int i = 0; i < 2; ++i){
    const float a = x[2*i], c = x[2*i+1];
    const __hip_bfloat162 hp = __float22bfloat162_rn(make_float2(a, c));
    unsigned hu; __builtin_memcpy(&hu, &hp, 4);
    H[i] = hu;
    const float ah = __uint_as_float(hu << 16);
    const float ch = __uint_as_float(hu & 0xFFFF0000u);
    const __hip_bfloat162 lp = __float22bfloat162_rn(make_float2(a - ah, c - ch));
    unsigned lu; __builtin_memcpy(&lu, &lp, 4);
    L[i] = lu;
  }
}

// ---------------- precompute kernels ----------------

__global__ __launch_bounds__(64)
void k_mlp(const float* __restrict__ Pplm,
           const float* __restrict__ Ws1, const float* __restrict__ bs1,
           const float* __restrict__ Ws2, const float* __restrict__ bs2,
           const float* __restrict__ Wg1, const float* __restrict__ bg1,
           const float* __restrict__ Wg2, const float* __restrict__ bg2,
           float* __restrict__ vv_ws, float* __restrict__ gn_ws)
{
  __shared__ float sH[64], sG[64], sgv[8];
  const int v = blockIdx.x, j = threadIdx.x;
  float a = bs1[j], g = bg1[j];
  for (int k = 0; k < 768; ++k){
    const float p = Pplm[v*768 + k];
    a = fmaf(p, Ws1[k*64 + j], a);
    g = fmaf(p, Wg1[k*64 + j], g);
  }
  sH[j] = fmaxf(a, 0.f);
  sG[j] = fmaxf(g, 0.f);
  __syncthreads();
  if (j < 5){
    float acc = bs2[j];
    for (int k = 0; k < 64; ++k) acc = fmaf(sH[k], Ws2[k*5 + j], acc);
    vv_ws[v*5 + j] = acc;
  }
  if (j < 8){
    float acc = bg2[j];
    for (int k = 0; k < 64; ++k) acc = fmaf(sG[k], Wg2[k*8 + j], acc);
    sgv[j] = acc;
  }
  __syncthreads();
  if (j == 0){
    float n = 0.f;
    for (int e = 0; e < 8; ++e) n += sgv[e]*sgv[e];
    n = fmaxf(sqrtf(n), 1e-12f);
    for (int e = 0; e < 8; ++e) gn_ws[v*8 + e] = sgv[e]/n;
  }
}

__global__ __launch_bounds__(64)
void k_adj(const float* __restrict__ gn_ws, float* __restrict__ adj_ws)
{
  const int v = blockIdx.x, j = threadIdx.x;
  float sc = 0.f;
  #pragma unroll
  for (int e = 0; e < 8; ++e) sc += gn_ws[v*8+e]*gn_ws[j*8+e];
  float mx = sc;
  for (int off = 32; off > 0; off >>= 1) mx = fmaxf(mx, __shfl_xor(mx, off));
  const float ex = __expf(sc - mx);
  float sm = ex;
  for (int off = 32; off > 0; off >>= 1) sm += __shfl_xor(sm, off);
  adj_ws[v*64 + j] = ex / sm;
}

__global__ __launch_bounds__(256)
void k_vto(const float* __restrict__ P, float* __restrict__ vto_ws)
{
  const int idx = blockIdx.x*256 + threadIdx.x;
  if (idx >= BB*VV) return;
  const int b = idx/VV, v = idx%VV;
  float s = 0.f;
  for (int t = 0; t < TT; ++t) s += P[((size_t)(b*TT+t))*128 + 64 + v];
  vto_ws[idx] = s;
}

// pack gate weights into per-lane MFMA B-fragments (bf16) + paired side tables
// frag id f = ((e*2 + kt)*2 + p); element (f*64 + lane)*8 + j
// ALL gates use K-order [x(0..31) | h(0..31)] with rarity (orig k=32) as side:
//   k' = kt*32 + (lane>>4)*8 + j ; orig_k = (k'<32) ? k' : k'+1
// side tables: [e][o][2] pairs -> {rarity weight, bias}
__global__ __launch_bounds__(256)
void k_bpack(const float* __restrict__ Wr, const float* __restrict__ br,
             const float* __restrict__ Wu, const float* __restrict__ bu,
             const float* __restrict__ Wc, const float* __restrict__ bc,
             unsigned short* __restrict__ Bru, unsigned short* __restrict__ Bcn,
             float* __restrict__ sideRU, float* __restrict__ sideC)
{
  const int idx = blockIdx.x*256 + threadIdx.x;
  if (idx < 20480){
    const int f = idx >> 9, rem = idx & 511, l = rem >> 3, j = rem & 7;
    const int p = f & 1, kt = (f>>1)&1, e = f>>2;
    const int kp = kt*32 + (l>>4)*8 + j;
    const int k = (kp < 32) ? kp : kp + 1;
    const int o = p*16 + (l&15);
    const int q = (e < 5) ? e : e - 5;
    const float* W = (e < 5) ? Wr : Wu;
    Bru[idx] = f2bf(W[(q*65 + k)*32 + o]);
  } else if (idx < 30720){
    const int i2 = idx - 20480;
    const int f = i2 >> 9, rem = i2 & 511, l = rem >> 3, j = rem & 7;
    const int p = f & 1, kt = (f>>1)&1, e = f>>2;
    const int kp = kt*32 + (l>>4)*8 + j;
    const int k = (kp < 32) ? kp : kp + 1;
    const int o = p*16 + (l&15);
    Bcn[i2] = f2bf(Wc[(e*65 + k)*32 + o]);
  } else if (idx < 31360){
    const int i3 = idx - 30720;            // [e:10][o:32][s:2] pairs
    const int e = i3 >> 6, rem = i3 & 63, o = rem >> 1, s = rem & 1;
    const int q = (e < 5) ? e : e - 5;
    float v;
    if (s == 0) v = (e < 5) ? Wr[(q*65 + 32)*32 + o] : Wu[(q*65 + 32)*32 + o]; // rarity weight
    else        v = (e < 5) ? br[q*32 + o] : bu[q*32 + o];
    sideRU[i3] = v;
  } else if (idx < 31680){
    const int i4 = idx - 31360;            // [e:5][o:32][s:2] pairs
    const int e = i4 >> 6, rem = i4 & 63, o = rem >> 1, s = rem & 1;
    sideC[i4] = s ? bc[e*32 + o] : Wc[(e*65 + 32)*32 + o];   // s=0: rarity weight
  }
}

// ---------------- main recurrent kernel: 1 block (512 thr / 8 waves) per batch ----------------
// wave (mq, ph): mq = wid>>1 owns rows R..R+15; ph = wid&1 owns o-half ph*16..+15.
// 3 barriers/step (LDS-only drain): comb->gates (A1f), r/u->cand (hrF), tail (B0T).

__global__ __launch_bounds__(512, 1)
void tedgn_main(const float* __restrict__ P, const float* __restrict__ Pstatic,
                const float* __restrict__ Pavg, const int* __restrict__ Plen,
                const float* __restrict__ Ptime,
                const float* __restrict__ w_val, const float* __restrict__ b_val,
                const float* __restrict__ w_per, const float* __restrict__ b_per,
                const float* __restrict__ w_lin, const float* __restrict__ b_lin,
                const float* __restrict__ emb1, const float* __restrict__ rarW,
                const float* __restrict__ Wse, const float* __restrict__ bse,
                const float* __restrict__ Wc1, const float* __restrict__ bc1,
                const float* __restrict__ Wc2, const float* __restrict__ bc2,
                const float* __restrict__ vv_ws, const float* __restrict__ adjb_ws,
                const float* __restrict__ vto_ws,
                const unsigned short* __restrict__ Bru_ws,
                const unsigned short* __restrict__ Bc_ws,
                const float* __restrict__ sideRU_ws, const float* __restrict__ sideC_ws,
                float* __restrict__ out)
{
  // XH^T double-buffered: [buf][hi/lo][feature 0..63 = x(32)|h(32)][v, pad 72]
  __shared__ __align__(16) unsigned short B0T[2][2][64][72];
  __shared__ __align__(16) unsigned short s_Wru[20480];   // gate weight B-fragments
  __shared__ __align__(16) unsigned short s_Wc[10240];
  __shared__ __align__(16) float A1f[4][16][68];   // per-mq comb rows (f32); col 64 = comb_rar
  __shared__ __align__(16) float hrF[4][16][36];   // per-mq h_r rows (f32)
  __shared__ __align__(16) float s_rar[2][64];
  __shared__ __align__(16) float s_m[2][64];
  __shared__ float s_sru[640], s_scd[320];
  __shared__ float s_outf[64][33];
  __shared__ float s_feat[128], s_hid[200];

  const int tid  = threadIdx.x;
  const int lane = tid & 63;
  const int wid  = tid >> 6;      // 8 waves
  const int mq   = wid >> 1;      // row quarter
  const int ph   = wid & 1;       // o-half
  const int l15  = lane & 15;
  const int l16g = lane >> 4;
  const int kgo  = l16g * 8;
  const int R    = mq * 16;
  const int v_own = R + l15;
  const int oo   = ph*16 + l15;
  const int b    = blockIdx.x;
  const int len  = Plen[b];

  // LDS fills: side tables + weight fragments
  for (int i = tid; i < 640; i += 512) s_sru[i] = sideRU_ws[i];
  for (int i = tid; i < 320; i += 512) s_scd[i] = sideC_ws[i];
  {
    const uint4* src1 = (const uint4*)Bru_ws;
    uint4* dst1 = (uint4*)s_Wru;
    for (int i = tid; i < 2560; i += 512) dst1[i] = src1[i];
    const uint4* src2 = (const uint4*)Bc_ws;
    uint4* dst2 = (uint4*)s_Wc;
    for (int i = tid; i < 1280; i += 512) dst2[i] = src2[i];
  }

  // per-lane constants (keyed on v_own; duplicated across ph waves)
  float adjb_r[2][8], rarW_r[2][8];
  #pragma unroll
  for (int kt = 0; kt < 2; ++kt)
    #pragma unroll
    for (int j = 0; j < 8; ++j){
      adjb_r[kt][j] = adjb_ws[v_own*64 + kt*32 + kgo + j];
      rarW_r[kt][j] = rarW   [v_own*64 + kt*32 + kgo + j];
    }
  float embr[8], wvr[8], bvr[8], wpr[8], bpr[8];
  #pragma unroll
  for (int j = 0; j < 8; ++j){
    const int d = kgo + j;
    embr[j] = emb1[v_own*DD + d];
    wvr[j]  = w_val[d];
    bvr[j]  = b_val[d];
    wpr[j]  = (d == 0) ? w_lin[0] : w_per[d-1];
    bpr[j]  = (d == 0) ? b_lin[0] : b_per[d-1];
  }
  float vvr[4][NQ];
  #pragma unroll
  for (int j = 0; j < 4; ++j)
    #pragma unroll
    for (int q = 0; q < NQ; ++q)
      vvr[j][q] = vv_ws[(R + l16g*4 + j)*NQ + q];
  const float vto_own = vto_ws[b*VV + v_own];

  float h[4]    = {0.f,0.f,0.f,0.f};     // rows R+l16g*4+j, col oo
  float outr[4] = {0.f,0.f,0.f,0.f};
  bfu xfH, xfL;
  float rar_own, m_own;

  // ---- prologue: build step-0 state into buf 0 ----
  {
    const float pd = P[(size_t)(b*TT)*128 + v_own];
    const float pm = P[(size_t)(b*TT)*128 + 64 + v_own];
    const float pa = Pavg[(size_t)(b*TT)*VV + v_own];
    const float pt = Ptime[b*TT];
    const float rar_n = 0.5f * tanhfast(pa / (vto_own + 1.f));
    float xv[8];
    #pragma unroll
    for (int j = 0; j < 8; ++j){
      const int d = kgo + j;
      const float tearg = fmaf(pt, wpr[j], bpr[j]);
      const float te = (d == 0) ? tearg : __sinf(tearg);
      const float ve = fmaxf(fmaf(pd, wvr[j], bvr[j]), 0.f);
      xv[j] = (ve + te + embr[j]) * pm;
    }
    split8(xv, xfH, xfL);
    if (ph == 0){
      #pragma unroll
      for (int j = 0; j < 8; ++j){
        B0T[0][0][kgo + j][v_own] = xfH.s[j];
        B0T[0][1][kgo + j][v_own] = xfL.s[j];
      }
      // zero h rows 32..47
      *(uint2*)&B0T[0][0][32 + l15][R + l16g*4] = make_uint2(0u, 0u);
      *(uint2*)&B0T[0][1][32 + l15][R + l16g*4] = make_uint2(0u, 0u);
      if (l16g == 0){
        s_rar[0][v_own] = rar_n;
        s_m[0][v_own]   = pm;
      }
    } else {
      // zero h rows 48..63
      *(uint2*)&B0T[0][0][48 + l15][R + l16g*4] = make_uint2(0u, 0u);
      *(uint2*)&B0T[0][1][48 + l15][R + l16g*4] = make_uint2(0u, 0u);
    }
    rar_own = rar_n;
    m_own   = pm;
  }
  __syncthreads();

  #pragma clang loop unroll(disable)
  for (int t = 0; t < TT; ++t){
    const int cur = t & 1, nxt = cur ^ 1;

    // prefetch t+1 (consumed in tail; stays in flight across bar_lgkm barriers)
    float pd = 0.f, pm = 0.f, pa = 0.f, pt = 0.f;
    const bool more = (t + 1 < TT);
    if (more){
      pd = P[(size_t)(b*TT + t + 1)*128 + v_own];
      pm = P[(size_t)(b*TT + t + 1)*128 + 64 + v_own];
      pa = Pavg[(size_t)(b*TT + t + 1)*VV + v_own];
      pt = Ptime[b*TT + t + 1];
    }

    // ---- Phase A: adj A-fragments + comb_rar + comb (2 N-tiles per wave) ----
    {
      bfu aAh[2], aAl[2];
      float crar = 0.f;
      #pragma unroll
      for (int kt = 0; kt < 2; ++kt){
        const float4 r0 = *(const float4*)&s_rar[cur][kt*32 + kgo];
        const float4 r1 = *(const float4*)&s_rar[cur][kt*32 + kgo + 4];
        const float4 m0 = *(const float4*)&s_m[cur][kt*32 + kgo];
        const float4 m1 = *(const float4*)&s_m[cur][kt*32 + kgo + 4];
        const float rj[8] = {r0.x,r0.y,r0.z,r0.w,r1.x,r1.y,r1.z,r1.w};
        const float mj[8] = {m0.x,m0.y,m0.z,m0.w,m1.x,m1.y,m1.z,m1.w};
        float av[8];
        #pragma unroll
        for (int j = 0; j < 8; ++j){
          const int k = kt*32 + kgo + j;
          const float e1 = fmaf(-rarW_r[kt][j], fabsf(rar_own - rj[j]), 1.0f);
          const float a  = adjb_r[kt][j] * e1 * (m_own * mj[j]);
          av[j] = (k == v_own) ? 1.0f : a;
          crar = fmaf(av[j], rj[j], crar);
        }
        split8(av, aAh[kt], aAl[kt]);
      }
      crar += __shfl_xor(crar, 16);
      crar += __shfl_xor(crar, 32);
      if (ph == 0 && l16g == 0) A1f[mq][l15][64] = crar;

      #pragma unroll
      for (int ni = 0; ni < 2; ++ni){
        const int n = 2*ph + ni;
        f32x4 acc = {0.f,0.f,0.f,0.f};
        #pragma unroll
        for (int kt = 0; kt < 2; ++kt){
          const bf16x8 bh = *(const bf16x8*)&B0T[cur][0][n*16 + l15][kt*32 + kgo];
          const bf16x8 bl = *(const bf16x8*)&B0T[cur][1][n*16 + l15][kt*32 + kgo];
          acc = MFMA(aAh[kt].v, bh, acc);
          acc = MFMA(aAl[kt].v, bh, acc);
          acc = MFMA(aAh[kt].v, bl, acc);
        }
        const int col = n*16 + l15;
        #pragma unroll
        for (int j = 0; j < 4; ++j) A1f[mq][l16g*4 + j][col] = acc[j];
      }
    }
    bar_lgkm();   // barrier 1: A1f complete (LDS-only drain)

    // ---- Phase B: gate A-fragments + r/u gates (own o-half only) ----
    float hr[4], uu[4];
    {
      bfu aH[2], aL[2];
      #pragma unroll
      for (int kt = 0; kt < 2; ++kt){
        float xv[8];
        *(float4*)&xv[0] = *(const float4*)&A1f[mq][l15][kt*32 + kgo];
        *(float4*)&xv[4] = *(const float4*)&A1f[mq][l15][kt*32 + kgo + 4];
        split8(xv, aH[kt], aL[kt]);
      }
      float a64f[4];
      #pragma unroll
      for (int j = 0; j < 4; ++j) a64f[j] = A1f[mq][l16g*4 + j][64];

      f32x4 ag[10];
      #pragma unroll
      for (int e = 0; e < 10; ++e){
        const float2 wb = *(const float2*)&s_sru[e*64 + oo*2];
        #pragma unroll
        for (int j = 0; j < 4; ++j) ag[e][j] = fmaf(a64f[j], wb.x, wb.y);
      }
      #pragma unroll
      for (int e = 0; e < 10; ++e){
        const bf16x8 w0 = *(const bf16x8*)&s_Wru[(((e*2+0)*2+ph)*64 + lane)*8];
        const bf16x8 w1 = *(const bf16x8*)&s_Wru[(((e*2+1)*2+ph)*64 + lane)*8];
        ag[e] = MFMA(aH[0].v, w0, ag[e]);
        ag[e] = MFMA(aL[0].v, w0, ag[e]);
        ag[e] = MFMA(aH[1].v, w1, ag[e]);
        ag[e] = MFMA(aL[1].v, w1, ag[e]);
      }
      #pragma unroll
      for (int j = 0; j < 4; ++j){
        const float pr = vvr[j][0]*ag[0][j] + vvr[j][1]*ag[1][j]
                       + vvr[j][2]*ag[2][j] + vvr[j][3]*ag[3][j]
                       + vvr[j][4]*ag[4][j];
        hr[j] = sigm(pr) * h[j];
        hrF[mq][l16g*4 + j][oo] = hr[j];
      }
      #pragma unroll
      for (int j = 0; j < 4; ++j){
        const float pu = vvr[j][0]*ag[5][j] + vvr[j][1]*ag[6][j]
                       + vvr[j][2]*ag[7][j] + vvr[j][3]*ag[8][j]
                       + vvr[j][4]*ag[9][j];
        uu[j] = sigm(pu);
      }
    }
    bar_lgkm();   // barrier 2: hrF complete

    // ---- Phase C: cand + GRU update + B0T[nxt] writes + next-step prep ----
    {
      bfu hH, hL;
      {
        float hv[8];
        *(float4*)&hv[0] = *(const float4*)&hrF[mq][l15][kgo];
        *(float4*)&hv[4] = *(const float4*)&hrF[mq][l15][kgo + 4];
        split8(hv, hH, hL);
      }
      float rar_cj[4], m_cj[4];
      #pragma unroll
      for (int j = 0; j < 4; ++j){
        rar_cj[j] = s_rar[cur][R + l16g*4 + j];
        m_cj[j]   = s_m[cur][R + l16g*4 + j];
      }
      f32x4 ag[5];
      #pragma unroll
      for (int e = 0; e < 5; ++e){
        const float2 wb = *(const float2*)&s_scd[e*64 + oo*2];
        #pragma unroll
        for (int j = 0; j < 4; ++j) ag[e][j] = fmaf(rar_cj[j], wb.x, wb.y);
      }
      #pragma unroll
      for (int e = 0; e < 5; ++e){
        const bf16x8 w0 = *(const bf16x8*)&s_Wc[(((e*2+0)*2+ph)*64 + lane)*8];
        const bf16x8 w1 = *(const bf16x8*)&s_Wc[(((e*2+1)*2+ph)*64 + lane)*8];
        ag[e] = MFMA(xfH.v, w0, ag[e]);
        ag[e] = MFMA(xfL.v, w0, ag[e]);
        ag[e] = MFMA(hH.v,  w1, ag[e]);
        ag[e] = MFMA(hL.v,  w1, ag[e]);
      }
      const bool snap = (t == len - 1);
      #pragma unroll
      for (int j = 0; j < 4; ++j){
        const float pc = vvr[j][0]*ag[0][j] + vvr[j][1]*ag[1][j]
                       + vvr[j][2]*ag[2][j] + vvr[j][3]*ag[3][j]
                       + vvr[j][4]*ag[4][j];
        const float cd = tanhfast(pc);
        const float hn = fmaf(uu[j], cd - hr[j], hr[j]);
        const float hf = (m_cj[j] > 0.5f) ? hn : h[j];
        h[j] = hf;
        if (snap) outr[j] = hf;
      }
      // write h to B0T[nxt] row 32+oo, cols R+l16g*4..+3
      {
        unsigned H2[2], L2[2];
        split4(h, H2, L2);
        *(uint2*)&B0T[nxt][0][32 + oo][R + l16g*4] = make_uint2(H2[0], H2[1]);
        *(uint2*)&B0T[nxt][1][32 + oo][R + l16g*4] = make_uint2(L2[0], L2[1]);
      }
      // next-step x / rar / m into buf nxt
      if (more){
        const float rar_n = 0.5f * tanhfast(pa / (vto_own + 1.f));
        float xv[8];
        #pragma unroll
        for (int j = 0; j < 8; ++j){
          const int d = kgo + j;
          const float tearg = fmaf(pt, wpr[j], bpr[j]);
          const float te = (d == 0) ? tearg : __sinf(tearg);
          const float ve = fmaxf(fmaf(pd, wvr[j], bvr[j]), 0.f);
          xv[j] = (ve + te + embr[j]) * pm;
        }
        split8(xv, xfH, xfL);
        if (ph == 0){
          #pragma unroll
          for (int j = 0; j < 8; ++j){
            B0T[nxt][0][kgo + j][v_own] = xfH.s[j];
            B0T[nxt][1][kgo + j][v_own] = xfL.s[j];
          }
          if (l16g == 0){
            s_rar[nxt][v_own] = rar_n;
            s_m[nxt][v_own]   = pm;
          }
        }
        rar_own = rar_n;
        m_own   = pm;
      }
    }
    bar_lgkm();   // barrier 3: B0T[nxt]/rar/m complete
  }

  // ---- epilogue: feat -> 200-unit MLP -> 2 logits ----
  #pragma unroll
  for (int j = 0; j < 4; ++j)
    s_outf[R + l16g*4 + j][oo] = outr[j];
  __syncthreads();
  if (tid < VV){
    float s = 0.f;
    #pragma unroll
    for (int d = 0; d < DD; ++d) s += s_outf[tid][d];
    s_feat[tid] = s;
  } else if (tid < 2*VV){
    const int v = tid - VV;
    float se = bse[v];
    #pragma unroll
    for (int k = 0; k < 16; ++k) se = fmaf(Pstatic[b*16 + k], Wse[k*VV + v], se);
    s_feat[VV + v] = se;
  }
  __syncthreads();
  if (tid < 200){
    float a = bc1[tid];
    for (int k = 0; k < 128; ++k) a = fmaf(s_feat[k], Wc1[k*200 + tid], a);
    s_hid[tid] = fmaxf(a, 0.f);
  }
  __syncthreads();
  if (tid < 2){
    float a = bc2[tid];
    for (int k = 0; k < 200; ++k) a = fmaf(s_hid[k], Wc2[k*2 + tid], a);
    out[b*2 + tid] = a;
  }
}

// ---------------- launch ----------------

extern "C" void kernel_launch(void* const* d_in, const int* in_sizes, int n_in,
                              void* d_out, int out_size, void* d_ws, size_t ws_size,
                              hipStream_t stream) {
  (void)in_sizes; (void)n_in; (void)out_size; (void)ws_size;
  const float* P       = (const float*)d_in[0];
  const float* Pstatic = (const float*)d_in[1];
  const float* Pavg    = (const float*)d_in[2];
  const int*   Plen    = (const int*)  d_in[3];
  const float* Ptime   = (const float*)d_in[4];
  const float* Pplm    = (const float*)d_in[5];
  const float* w_val   = (const float*)d_in[6];
  const float* b_val   = (const float*)d_in[7];
  const float* w_per   = (const float*)d_in[8];
  const float* b_per   = (const float*)d_in[9];
  const float* w_lin   = (const float*)d_in[10];
  const float* b_lin   = (const float*)d_in[11];
  const float* emb1    = (const float*)d_in[12];
  const float* Ws1     = (const float*)d_in[13];
  const float* bs1     = (const float*)d_in[14];
  const float* Ws2     = (const float*)d_in[15];
  const float* bs2     = (const float*)d_in[16];
  const float* Wg1     = (const float*)d_in[17];
  const float* bg1     = (const float*)d_in[18];
  const float* Wg2     = (const float*)d_in[19];
  const float* bg2     = (const float*)d_in[20];
  const float* rarW    = (const float*)d_in[21];
  const float* Wu      = (const float*)d_in[22];
  const float* bu      = (const float*)d_in[23];
  const float* Wr      = (const float*)d_in[24];
  const float* br      = (const float*)d_in[25];
  const float* Wcand   = (const float*)d_in[26];
  const float* bcand   = (const float*)d_in[27];
  const float* Wse     = (const float*)d_in[28];
  const float* bse     = (const float*)d_in[29];
  const float* Wc1     = (const float*)d_in[30];
  const float* bc1     = (const float*)d_in[31];
  const float* Wc2     = (const float*)d_in[32];
  const float* bc2     = (const float*)d_in[33];

  float* ws = (float*)d_ws;
  float*          vv_ws   = ws;                 // 320 f
  float*          gn_ws   = ws + 320;           // 512 f
  float*          adjb_ws = ws + 832;           // 4096 f
  float*          vto_ws  = ws + 4928;          // 8192 f
  unsigned short* Bru_ws  = (unsigned short*)(ws + 13120);   // 20480 u16
  unsigned short* Bc_ws   = (unsigned short*)(ws + 23360);   // 10240 u16
  float*          sideRU_ws = ws + 28480;       // 640 f
  float*          sideC_ws  = ws + 29120;       // 320 f

  k_mlp  <<<64, 64, 0, stream>>>(Pplm, Ws1, bs1, Ws2, bs2, Wg1, bg1, Wg2, bg2, vv_ws, gn_ws);
  k_adj  <<<64, 64, 0, stream>>>(gn_ws, adjb_ws);
  k_vto  <<<(BB*VV + 255)/256, 256, 0, stream>>>(P, vto_ws);
  k_bpack<<<124, 256, 0, stream>>>(Wr, br, Wu, bu, Wcand, bcand, Bru_ws, Bc_ws, sideRU_ws, sideC_ws);

  tedgn_main<<<BB, 512, 0, stream>>>(P, Pstatic, Pavg, Plen, Ptime,
                                     w_val, b_val, w_per, b_per, w_lin, b_lin,
                                     emb1, rarW, Wse, bse, Wc1, bc1, Wc2, bc2,
                                     vv_ws, adjb_ws, vto_ws,
                                     Bru_ws, Bc_ws, sideRU_ws, sideC_ws,
                                     (float*)d_out);
}

// Round 15
// 582.911 us; speedup vs baseline: 1.2721x; 1.0015x over previous
//
#include <hip/hip_runtime.h>
#include <hip/hip_bf16.h>
#include <math.h>

#define BB 128
#define TT 128
#define VV 64
#define DD 32
#define NQ 5

typedef short bf16x8 __attribute__((ext_vector_type(8)));
typedef float f32x4 __attribute__((ext_vector_type(4)));

#define MFMA(a,b,c) __builtin_amdgcn_mfma_f32_16x16x32_bf16(a,b,c,0,0,0)

// barrier with LDS-only drain: DS producer/consumer ordering preserved via
// lgkmcnt(0); global loads (register-private prefetch) stay in flight.
__device__ __forceinline__ void bar_lgkm(){
  asm volatile("s_waitcnt lgkmcnt(0)" ::: "memory");
  __builtin_amdgcn_s_barrier();
  asm volatile("" ::: "memory");
}

__device__ __forceinline__ float sigm(float x){ return 1.0f/(1.0f+__expf(-x)); }
__device__ __forceinline__ float tanhfast(float x){ return 2.0f/(1.0f+__expf(-2.0f*x)) - 1.0f; }
__device__ __forceinline__ unsigned short f2bf(float x){
  unsigned u = __float_as_uint(x);
  u += 0x7FFFu + ((u>>16)&1u);
  return (unsigned short)(u>>16);
}
__device__ __forceinline__ float bf2f(unsigned short h){
  return __uint_as_float(((unsigned)h)<<16);
}

union bfu { bf16x8 v; unsigned u[4]; unsigned short s[8]; };

// split 8 floats -> hi bf16x8 + lo bf16x8 (lo = rne(x - f32(hi))) via cvt_pk (RNE)
__device__ __forceinline__ void split8(const float* x, bfu& H, bfu& L){
  #pragma unroll
  for (int i = 0; i < 4; ++i){
    const float a = x[2*i], c = x[2*i+1];
    const __hip_bfloat162 hp = __float22bfloat162_rn(make_float2(a, c));
    unsigned hu; __builtin_memcpy(&hu, &hp, 4);
    H.u[i] = hu;
    const float ah = __uint_as_float(hu << 16);
    const float ch = __uint_as_float(hu & 0xFFFF0000u);
    const __hip_bfloat162 lp = __float22bfloat162_rn(make_float2(a - ah, c - ch));
    unsigned lu; __builtin_memcpy(&lu, &lp, 4);
    L.u[i] = lu;
  }
}

// split 4 floats -> 2x uint (4 bf16 hi) + 2x uint (4 bf16 lo)
__device__ __forceinline__ void split4(const float* x, unsigned* H, unsigned* L){
  #pragma unroll
  for (int i = 0; i < 2; ++i){
    const float a = x[2*i], c = x[2*i+1];
    const __hip_bfloat162 hp = __float22bfloat162_rn(make_float2(a, c));
    unsigned hu; __builtin_memcpy(&hu, &hp, 4);
    H[i] = hu;
    const float ah = __uint_as_float(hu << 16);
    const float ch = __uint_as_float(hu & 0xFFFF0000u);
    const __hip_bfloat162 lp = __float22bfloat162_rn(make_float2(a - ah, c - ch));
    unsigned lu; __builtin_memcpy(&lu, &lp, 4);
    L[i] = lu;
  }
}

// ---------------- precompute kernels ----------------

__global__ __launch_bounds__(64)
void k_mlp(const float* __restrict__ Pplm,
           const float* __restrict__ Ws1, const float* __restrict__ bs1,
           const float* __restrict__ Ws2, const float* __restrict__ bs2,
           const float* __restrict__ Wg1, const float* __restrict__ bg1,
           const float* __restrict__ Wg2, const float* __restrict__ bg2,
           float* __restrict__ vv_ws, float* __restrict__ gn_ws)
{
  __shared__ float sH[64], sG[64], sgv[8];
  const int v = blockIdx.x, j = threadIdx.x;
  float a = bs1[j], g = bg1[j];
  for (int k = 0; k < 768; ++k){
    const float p = Pplm[v*768 + k];
    a = fmaf(p, Ws1[k*64 + j], a);
    g = fmaf(p, Wg1[k*64 + j], g);
  }
  sH[j] = fmaxf(a, 0.f);
  sG[j] = fmaxf(g, 0.f);
  __syncthreads();
  if (j < 5){
    float acc = bs2[j];
    for (int k = 0; k < 64; ++k) acc = fmaf(sH[k], Ws2[k*5 + j], acc);
    vv_ws[v*5 + j] = acc;
  }
  if (j < 8){
    float acc = bg2[j];
    for (int k = 0; k < 64; ++k) acc = fmaf(sG[k], Wg2[k*8 + j], acc);
    sgv[j] = acc;
  }
  __syncthreads();
  if (j == 0){
    float n = 0.f;
    for (int e = 0; e < 8; ++e) n += sgv[e]*sgv[e];
    n = fmaxf(sqrtf(n), 1e-12f);
    for (int e = 0; e < 8; ++e) gn_ws[v*8 + e] = sgv[e]/n;
  }
}

__global__ __launch_bounds__(64)
void k_adj(const float* __restrict__ gn_ws, float* __restrict__ adj_ws)
{
  const int v = blockIdx.x, j = threadIdx.x;
  float sc = 0.f;
  #pragma unroll
  for (int e = 0; e < 8; ++e) sc += gn_ws[v*8+e]*gn_ws[j*8+e];
  float mx = sc;
  for (int off = 32; off > 0; off >>= 1) mx = fmaxf(mx, __shfl_xor(mx, off));
  const float ex = __expf(sc - mx);
  float sm = ex;
  for (int off = 32; off > 0; off >>= 1) sm += __shfl_xor(sm, off);
  adj_ws[v*64 + j] = ex / sm;
}

__global__ __launch_bounds__(256)
void k_vto(const float* __restrict__ P, float* __restrict__ vto_ws)
{
  const int idx = blockIdx.x*256 + threadIdx.x;
  if (idx >= BB*VV) return;
  const int b = idx/VV, v = idx%VV;
  float s = 0.f;
  for (int t = 0; t < TT; ++t) s += P[((size_t)(b*TT+t))*128 + 64 + v];
  vto_ws[idx] = s;
}

// pack gate weights into per-lane MFMA B-fragments (bf16) + paired side tables
// frag id f = ((e*2 + kt)*2 + p); element (f*64 + lane)*8 + j
// ALL gates use K-order [x(0..31) | h(0..31)] with rarity (orig k=32) as side:
//   k' = kt*32 + (lane>>4)*8 + j ; orig_k = (k'<32) ? k' : k'+1
// side tables: [e][o][2] pairs -> {rarity weight, bias}
__global__ __launch_bounds__(256)
void k_bpack(const float* __restrict__ Wr, const float* __restrict__ br,
             const float* __restrict__ Wu, const float* __restrict__ bu,
             const float* __restrict__ Wc, const float* __restrict__ bc,
             unsigned short* __restrict__ Bru, unsigned short* __restrict__ Bcn,
             float* __restrict__ sideRU, float* __restrict__ sideC)
{
  const int idx = blockIdx.x*256 + threadIdx.x;
  if (idx < 20480){
    const int f = idx >> 9, rem = idx & 511, l = rem >> 3, j = rem & 7;
    const int p = f & 1, kt = (f>>1)&1, e = f>>2;
    const int kp = kt*32 + (l>>4)*8 + j;
    const int k = (kp < 32) ? kp : kp + 1;
    const int o = p*16 + (l&15);
    const int q = (e < 5) ? e : e - 5;
    const float* W = (e < 5) ? Wr : Wu;
    Bru[idx] = f2bf(W[(q*65 + k)*32 + o]);
  } else if (idx < 30720){
    const int i2 = idx - 20480;
    const int f = i2 >> 9, rem = i2 & 511, l = rem >> 3, j = rem & 7;
    const int p = f & 1, kt = (f>>1)&1, e = f>>2;
    const int kp = kt*32 + (l>>4)*8 + j;
    const int k = (kp < 32) ? kp : kp + 1;
    const int o = p*16 + (l&15);
    Bcn[i2] = f2bf(Wc[(e*65 + k)*32 + o]);
  } else if (idx < 31360){
    const int i3 = idx - 30720;            // [e:10][o:32][s:2] pairs
    const int e = i3 >> 6, rem = i3 & 63, o = rem >> 1, s = rem & 1;
    const int q = (e < 5) ? e : e - 5;
    float v;
    if (s == 0) v = (e < 5) ? Wr[(q*65 + 32)*32 + o] : Wu[(q*65 + 32)*32 + o]; // rarity weight
    else        v = (e < 5) ? br[q*32 + o] : bu[q*32 + o];
    sideRU[i3] = v;
  } else if (idx < 31680){
    const int i4 = idx - 31360;            // [e:5][o:32][s:2] pairs
    const int e = i4 >> 6, rem = i4 & 63, o = rem >> 1, s = rem & 1;
    sideC[i4] = s ? bc[e*32 + o] : Wc[(e*65 + 32)*32 + o];   // s=0: rarity weight
  }
}

// ---------------- main recurrent kernel: 1 block (512 thr / 8 waves) per batch ----------------
// wave (mq, ph): mq = wid>>1 owns rows R..R+15; ph = wid&1 owns o-half ph*16..+15.
// 3 barriers/step (LDS-only drain): comb->gates (A1f), r/u->cand (hrF), tail (B0T).

__global__ __launch_bounds__(512, 1)
void tedgn_main(const float* __restrict__ P, const float* __restrict__ Pstatic,
                const float* __restrict__ Pavg, const int* __restrict__ Plen,
                const float* __restrict__ Ptime,
                const float* __restrict__ w_val, const float* __restrict__ b_val,
                const float* __restrict__ w_per, const float* __restrict__ b_per,
                const float* __restrict__ w_lin, const float* __restrict__ b_lin,
                const float* __restrict__ emb1, const float* __restrict__ rarW,
                const float* __restrict__ Wse, const float* __restrict__ bse,
                const float* __restrict__ Wc1, const float* __restrict__ bc1,
                const float* __restrict__ Wc2, const float* __restrict__ bc2,
                const float* __restrict__ vv_ws, const float* __restrict__ adjb_ws,
                const float* __restrict__ vto_ws,
                const unsigned short* __restrict__ Bru_ws,
                const unsigned short* __restrict__ Bc_ws,
                const float* __restrict__ sideRU_ws, const float* __restrict__ sideC_ws,
                float* __restrict__ out)
{
  // XH^T double-buffered: [buf][hi/lo][feature 0..63 = x(32)|h(32)][v, pad 72]
  __shared__ __align__(16) unsigned short B0T[2][2][64][72];
  __shared__ __align__(16) unsigned short s_Wru[20480];   // gate weight B-fragments
  __shared__ __align__(16) unsigned short s_Wc[10240];
  __shared__ __align__(16) float A1f[4][16][68];   // per-mq comb rows (f32); col 64 = comb_rar
  __shared__ __align__(16) float hrF[4][16][36];   // per-mq h_r rows (f32)
  __shared__ __align__(16) float s_rar[2][64];
  __shared__ __align__(16) float s_m[2][64];
  __shared__ float s_sru[640], s_scd[320];
  __shared__ float s_outf[64][33];
  __shared__ float s_feat[128], s_hid[200];

  const int tid  = threadIdx.x;
  const int lane = tid & 63;
  const int wid  = tid >> 6;      // 8 waves
  const int mq   = wid >> 1;      // row quarter
  const int ph   = wid & 1;       // o-half
  const int l15  = lane & 15;
  const int l16g = lane >> 4;
  const int kgo  = l16g * 8;
  const int R    = mq * 16;
  const int v_own = R + l15;
  const int oo   = ph*16 + l15;
  const int b    = blockIdx.x;
  const int len  = Plen[b];

  // LDS fills: side tables + weight fragments
  for (int i = tid; i < 640; i += 512) s_sru[i] = sideRU_ws[i];
  for (int i = tid; i < 320; i += 512) s_scd[i] = sideC_ws[i];
  {
    const uint4* src1 = (const uint4*)Bru_ws;
    uint4* dst1 = (uint4*)s_Wru;
    for (int i = tid; i < 2560; i += 512) dst1[i] = src1[i];
    const uint4* src2 = (const uint4*)Bc_ws;
    uint4* dst2 = (uint4*)s_Wc;
    for (int i = tid; i < 1280; i += 512) dst2[i] = src2[i];
  }

  // per-lane constants (keyed on v_own; duplicated across ph waves)
  float adjb_r[2][8], rarW_r[2][8];
  #pragma unroll
  for (int kt = 0; kt < 2; ++kt)
    #pragma unroll
    for (int j = 0; j < 8; ++j){
      adjb_r[kt][j] = adjb_ws[v_own*64 + kt*32 + kgo + j];
      rarW_r[kt][j] = rarW   [v_own*64 + kt*32 + kgo + j];
    }
  float embr[8], wvr[8], bvr[8], wpr[8], bpr[8];
  #pragma unroll
  for (int j = 0; j < 8; ++j){
    const int d = kgo + j;
    embr[j] = emb1[v_own*DD + d];
    wvr[j]  = w_val[d];
    bvr[j]  = b_val[d];
    wpr[j]  = (d == 0) ? w_lin[0] : w_per[d-1];
    bpr[j]  = (d == 0) ? b_lin[0] : b_per[d-1];
  }
  float vvr[4][NQ];
  #pragma unroll
  for (int j = 0; j < 4; ++j)
    #pragma unroll
    for (int q = 0; q < NQ; ++q)
      vvr[j][q] = vv_ws[(R + l16g*4 + j)*NQ + q];
  const float vto_own = vto_ws[b*VV + v_own];

  float h[4]    = {0.f,0.f,0.f,0.f};     // rows R+l16g*4+j, col oo
  float outr[4] = {0.f,0.f,0.f,0.f};
  bfu xfH, xfL;
  float rar_own, m_own;

  // ---- prologue: build step-0 state into buf 0 ----
  {
    const float pd = P[(size_t)(b*TT)*128 + v_own];
    const float pm = P[(size_t)(b*TT)*128 + 64 + v_own];
    const float pa = Pavg[(size_t)(b*TT)*VV + v_own];
    const float pt = Ptime[b*TT];
    const float rar_n = 0.5f * tanhfast(pa / (vto_own + 1.f));
    float xv[8];
    #pragma unroll
    for (int j = 0; j < 8; ++j){
      const int d = kgo + j;
      const float tearg = fmaf(pt, wpr[j], bpr[j]);
      const float te = (d == 0) ? tearg : __sinf(tearg);
      const float ve = fmaxf(fmaf(pd, wvr[j], bvr[j]), 0.f);
      xv[j] = (ve + te + embr[j]) * pm;
    }
    split8(xv, xfH, xfL);
    if (ph == 0){
      #pragma unroll
      for (int j = 0; j < 8; ++j){
        B0T[0][0][kgo + j][v_own] = xfH.s[j];
        B0T[0][1][kgo + j][v_own] = xfL.s[j];
      }
      // zero h rows 32..47
      *(uint2*)&B0T[0][0][32 + l15][R + l16g*4] = make_uint2(0u, 0u);
      *(uint2*)&B0T[0][1][32 + l15][R + l16g*4] = make_uint2(0u, 0u);
      if (l16g == 0){
        s_rar[0][v_own] = rar_n;
        s_m[0][v_own]   = pm;
      }
    } else {
      // zero h rows 48..63
      *(uint2*)&B0T[0][0][48 + l15][R + l16g*4] = make_uint2(0u, 0u);
      *(uint2*)&B0T[0][1][48 + l15][R + l16g*4] = make_uint2(0u, 0u);
    }
    rar_own = rar_n;
    m_own   = pm;
  }
  __syncthreads();

  #pragma clang loop unroll(disable)
  for (int t = 0; t < TT; ++t){
    const int cur = t & 1, nxt = cur ^ 1;

    // prefetch t+1 (consumed in tail; stays in flight across bar_lgkm barriers)
    float pd = 0.f, pm = 0.f, pa = 0.f, pt = 0.f;
    const bool more = (t + 1 < TT);
    if (more){
      pd = P[(size_t)(b*TT + t + 1)*128 + v_own];
      pm = P[(size_t)(b*TT + t + 1)*128 + 64 + v_own];
      pa = Pavg[(size_t)(b*TT + t + 1)*VV + v_own];
      pt = Ptime[b*TT + t + 1];
    }

    // ---- Phase A: adj A-fragments + comb_rar + comb (2 N-tiles per wave) ----
    {
      bfu aAh[2], aAl[2];
      float crar = 0.f;
      #pragma unroll
      for (int kt = 0; kt < 2; ++kt){
        const float4 r0 = *(const float4*)&s_rar[cur][kt*32 + kgo];
        const float4 r1 = *(const float4*)&s_rar[cur][kt*32 + kgo + 4];
        const float4 m0 = *(const float4*)&s_m[cur][kt*32 + kgo];
        const float4 m1 = *(const float4*)&s_m[cur][kt*32 + kgo + 4];
        const float rj[8] = {r0.x,r0.y,r0.z,r0.w,r1.x,r1.y,r1.z,r1.w};
        const float mj[8] = {m0.x,m0.y,m0.z,m0.w,m1.x,m1.y,m1.z,m1.w};
        float av[8];
        #pragma unroll
        for (int j = 0; j < 8; ++j){
          const int k = kt*32 + kgo + j;
          const float e1 = fmaf(-rarW_r[kt][j], fabsf(rar_own - rj[j]), 1.0f);
          const float a  = adjb_r[kt][j] * e1 * (m_own * mj[j]);
          av[j] = (k == v_own) ? 1.0f : a;
          crar = fmaf(av[j], rj[j], crar);
        }
        split8(av, aAh[kt], aAl[kt]);
      }
      crar += __shfl_xor(crar, 16);
      crar += __shfl_xor(crar, 32);
      if (ph == 0 && l16g == 0) A1f[mq][l15][64] = crar;

      #pragma unroll
      for (int ni = 0; ni < 2; ++ni){
        const int n = 2*ph + ni;
        f32x4 acc = {0.f,0.f,0.f,0.f};
        #pragma unroll
        for (int kt = 0; kt < 2; ++kt){
          const bf16x8 bh = *(const bf16x8*)&B0T[cur][0][n*16 + l15][kt*32 + kgo];
          const bf16x8 bl = *(const bf16x8*)&B0T[cur][1][n*16 + l15][kt*32 + kgo];
          acc = MFMA(aAh[kt].v, bh, acc);
          acc = MFMA(aAl[kt].v, bh, acc);
          acc = MFMA(aAh[kt].v, bl, acc);
        }
        const int col = n*16 + l15;
        #pragma unroll
        for (int j = 0; j < 4; ++j) A1f[mq][l16g*4 + j][col] = acc[j];
      }
    }
    bar_lgkm();   // barrier 1: A1f complete (LDS-only drain)

    // ---- Phase B: gate A-fragments + r/u gates (own o-half only) ----
    float hr[4], uu[4];
    {
      bfu aH[2], aL[2];
      #pragma unroll
      for (int kt = 0; kt < 2; ++kt){
        float xv[8];
        *(float4*)&xv[0] = *(const float4*)&A1f[mq][l15][kt*32 + kgo];
        *(float4*)&xv[4] = *(const float4*)&A1f[mq][l15][kt*32 + kgo + 4];
        split8(xv, aH[kt], aL[kt]);
      }
      float a64f[4];
      #pragma unroll
      for (int j = 0; j < 4; ++j) a64f[j] = A1f[mq][l16g*4 + j][64];

      f32x4 ag[10];
      #pragma unroll
      for (int e = 0; e < 10; ++e){
        const float2 wb = *(const float2*)&s_sru[e*64 + oo*2];
        #pragma unroll
        for (int j = 0; j < 4; ++j) ag[e][j] = fmaf(a64f[j], wb.x, wb.y);
      }
      #pragma unroll
      for (int e = 0; e < 10; ++e){
        const bf16x8 w0 = *(const bf16x8*)&s_Wru[(((e*2+0)*2+ph)*64 + lane)*8];
        const bf16x8 w1 = *(const bf16x8*)&s_Wru[(((e*2+1)*2+ph)*64 + lane)*8];
        ag[e] = MFMA(aH[0].v, w0, ag[e]);
        ag[e] = MFMA(aL[0].v, w0, ag[e]);
        ag[e] = MFMA(aH[1].v, w1, ag[e]);
        ag[e] = MFMA(aL[1].v, w1, ag[e]);
      }
      #pragma unroll
      for (int j = 0; j < 4; ++j){
        const float pr = vvr[j][0]*ag[0][j] + vvr[j][1]*ag[1][j]
                       + vvr[j][2]*ag[2][j] + vvr[j][3]*ag[3][j]
                       + vvr[j][4]*ag[4][j];
        hr[j] = sigm(pr) * h[j];
        hrF[mq][l16g*4 + j][oo] = hr[j];
      }
      #pragma unroll
      for (int j = 0; j < 4; ++j){
        const float pu = vvr[j][0]*ag[5][j] + vvr[j][1]*ag[6][j]
                       + vvr[j][2]*ag[7][j] + vvr[j][3]*ag[8][j]
                       + vvr[j][4]*ag[9][j];
        uu[j] = sigm(pu);
      }
    }
    bar_lgkm();   // barrier 2: hrF complete

    // ---- Phase C: cand + GRU update + B0T[nxt] writes + next-step prep ----
    {
      bfu hH, hL;
      {
        float hv[8];
        *(float4*)&hv[0] = *(const float4*)&hrF[mq][l15][kgo];
        *(float4*)&hv[4] = *(const float4*)&hrF[mq][l15][kgo + 4];
        split8(hv, hH, hL);
      }
      float rar_cj[4], m_cj[4];
      #pragma unroll
      for (int j = 0; j < 4; ++j){
        rar_cj[j] = s_rar[cur][R + l16g*4 + j];
        m_cj[j]   = s_m[cur][R + l16g*4 + j];
      }
      f32x4 ag[5];
      #pragma unroll
      for (int e = 0; e < 5; ++e){
        const float2 wb = *(const float2*)&s_scd[e*64 + oo*2];
        #pragma unroll
        for (int j = 0; j < 4; ++j) ag[e][j] = fmaf(rar_cj[j], wb.x, wb.y);
      }
      #pragma unroll
      for (int e = 0; e < 5; ++e){
        const bf16x8 w0 = *(const bf16x8*)&s_Wc[(((e*2+0)*2+ph)*64 + lane)*8];
        const bf16x8 w1 = *(const bf16x8*)&s_Wc[(((e*2+1)*2+ph)*64 + lane)*8];
        ag[e] = MFMA(xfH.v, w0, ag[e]);
        ag[e] = MFMA(xfL.v, w0, ag[e]);
        ag[e] = MFMA(hH.v,  w1, ag[e]);
        ag[e] = MFMA(hL.v,  w1, ag[e]);
      }
      const bool snap = (t == len - 1);
      #pragma unroll
      for (int j = 0; j < 4; ++j){
        const float pc = vvr[j][0]*ag[0][j] + vvr[j][1]*ag[1][j]
                       + vvr[j][2]*ag[2][j] + vvr[j][3]*ag[3][j]
                       + vvr[j][4]*ag[4][j];
        const float cd = tanhfast(pc);
        const float hn = fmaf(uu[j], cd - hr[j], hr[j]);
        const float hf = (m_cj[j] > 0.5f) ? hn : h[j];
        h[j] = hf;
        if (snap) outr[j] = hf;
      }
      // write h to B0T[nxt] row 32+oo, cols R+l16g*4..+3
      {
        unsigned H2[2], L2[2];
        split4(h, H2, L2);
        *(uint2*)&B0T[nxt][0][32 + oo][R + l16g*4] = make_uint2(H2[0], H2[1]);
        *(uint2*)&B0T[nxt][1][32 + oo][R + l16g*4] = make_uint2(L2[0], L2[1]);
      }
      // next-step x / rar / m into buf nxt
      if (more){
        const float rar_n = 0.5f * tanhfast(pa / (vto_own + 1.f));
        float xv[8];
        #pragma unroll
        for (int j = 0; j < 8; ++j){
          const int d = kgo + j;
          const float tearg = fmaf(pt, wpr[j], bpr[j]);
          const float te = (d == 0) ? tearg : __sinf(tearg);
          const float ve = fmaxf(fmaf(pd, wvr[j], bvr[j]), 0.f);
          xv[j] = (ve + te + embr[j]) * pm;
        }
        split8(xv, xfH, xfL);
        if (ph == 0){
          #pragma unroll
          for (int j = 0; j < 8; ++j){
            B0T[nxt][0][kgo + j][v_own] = xfH.s[j];
            B0T[nxt][1][kgo + j][v_own] = xfL.s[j];
          }
          if (l16g == 0){
            s_rar[nxt][v_own] = rar_n;
            s_m[nxt][v_own]   = pm;
          }
        }
        rar_own = rar_n;
        m_own   = pm;
      }
    }
    bar_lgkm();   // barrier 3: B0T[nxt]/rar/m complete
  }

  // ---- epilogue: feat -> 200-unit MLP -> 2 logits ----
  #pragma unroll
  for (int j = 0; j < 4; ++j)
    s_outf[R + l16g*4 + j][oo] = outr[j];
  __syncthreads();
  if (tid < VV){
    float s = 0.f;
    #pragma unroll
    for (int d = 0; d < DD; ++d) s += s_outf[tid][d];
    s_feat[tid] = s;
  } else if (tid < 2*VV){
    const int v = tid - VV;
    float se = bse[v];
    #pragma unroll
    for (int k = 0; k < 16; ++k) se = fmaf(Pstatic[b*16 + k], Wse[k*VV + v], se);
    s_feat[VV + v] = se;
  }
  __syncthreads();
  if (tid < 200){
    float a = bc1[tid];
    for (int k = 0; k < 128; ++k) a = fmaf(s_feat[k], Wc1[k*200 + tid], a);
    s_hid[tid] = fmaxf(a, 0.f);
  }
  __syncthreads();
  if (tid < 2){
    float a = bc2[tid];
    for (int k = 0; k < 200; ++k) a = fmaf(s_hid[k], Wc2[k*2 + tid], a);
    out[b*2 + tid] = a;
  }
}

// ---------------- launch ----------------

extern "C" void kernel_launch(void* const* d_in, const int* in_sizes, int n_in,
                              void* d_out, int out_size, void* d_ws, size_t ws_size,
                              hipStream_t stream) {
  (void)in_sizes; (void)n_in; (void)out_size; (void)ws_size;
  const float* P       = (const float*)d_in[0];
  const float* Pstatic = (const float*)d_in[1];
  const float* Pavg    = (const float*)d_in[2];
  const int*   Plen    = (const int*)  d_in[3];
  const float* Ptime   = (const float*)d_in[4];
  const float* Pplm    = (const float*)d_in[5];
  const float* w_val   = (const float*)d_in[6];
  const float* b_val   = (const float*)d_in[7];
  const float* w_per   = (const float*)d_in[8];
  const float* b_per   = (const float*)d_in[9];
  const float* w_lin   = (const float*)d_in[10];
  const float* b_lin   = (const float*)d_in[11];
  const float* emb1    = (const float*)d_in[12];
  const float* Ws1     = (const float*)d_in[13];
  const float* bs1     = (const float*)d_in[14];
  const float* Ws2     = (const float*)d_in[15];
  const float* bs2     = (const float*)d_in[16];
  const float* Wg1     = (const float*)d_in[17];
  const float* bg1     = (const float*)d_in[18];
  const float* Wg2     = (const float*)d_in[19];
  const float* bg2     = (const float*)d_in[20];
  const float* rarW    = (const float*)d_in[21];
  const float* Wu      = (const float*)d_in[22];
  const float* bu      = (const float*)d_in[23];
  const float* Wr      = (const float*)d_in[24];
  const float* br      = (const float*)d_in[25];
  const float* Wcand   = (const float*)d_in[26];
  const float* bcand   = (const float*)d_in[27];
  const float* Wse     = (const float*)d_in[28];
  const float* bse     = (const float*)d_in[29];
  const float* Wc1     = (const float*)d_in[30];
  const float* bc1     = (const float*)d_in[31];
  const float* Wc2     = (const float*)d_in[32];
  const float* bc2     = (const float*)d_in[33];

  float* ws = (float*)d_ws;
  float*          vv_ws   = ws;                 // 320 f
  float*          gn_ws   = ws + 320;           // 512 f
  float*          adjb_ws = ws + 832;           // 4096 f
  float*          vto_ws  = ws + 4928;          // 8192 f
  unsigned short* Bru_ws  = (unsigned short*)(ws + 13120);   // 20480 u16
  unsigned short* Bc_ws   = (unsigned short*)(ws + 23360);   // 10240 u16
  float*          sideRU_ws = ws + 28480;       // 640 f
  float*          sideC_ws  = ws + 29120;       // 320 f

  k_mlp  <<<64, 64, 0, stream>>>(Pplm, Ws1, bs1, Ws2, bs2, Wg1, bg1, Wg2, bg2, vv_ws, gn_ws);
  k_adj  <<<64, 64, 0, stream>>>(gn_ws, adjb_ws);
  k_vto  <<<(BB*VV + 255)/256, 256, 0, stream>>>(P, vto_ws);
  k_bpack<<<124, 256, 0, stream>>>(Wr, br, Wu, bu, Wcand, bcand, Bru_ws, Bc_ws, sideRU_ws, sideC_ws);

  tedgn_main<<<BB, 512, 0, stream>>>(P, Pstatic, Pavg, Plen, Ptime,
                                     w_val, b_val, w_per, b_per, w_lin, b_lin,
                                     emb1, rarW, Wse, bse, Wc1, bc1, Wc2, bc2,
                                     vv_ws, adjb_ws, vto_ws,
                                     Bru_ws, Bc_ws, sideRU_ws, sideC_ws,
                                     (float*)d_out);
}